// Round 2
// baseline (261.042 us; speedup 1.0000x reference)
//
#include <hip/hip_runtime.h>
#include <math.h>

#define L 16384
#define H 128
#define P 256
#define CL 64
#define NCH (L/CL)

struct Params { float M11,M12,M21,M22,s1,s2; };

__device__ inline Params get_params(const float* A_diag, const float* steps, int p){
  float A = A_diag[p]; A = A > 0.f ? A : 0.f;          // relu
  float dt = 1.f/(1.f + expf(-steps[p]));              // sigmoid
  float schur = 1.f/(1.f + dt*dt*A);
  Params q;
  q.M11 = 1.f - dt*dt*A*schur;
  q.M12 = -dt*A*schur;
  q.M21 = dt*schur;
  q.M22 = schur;
  q.s1 = q.M11*dt;   // F1 = M11*dt*Bu
  q.s2 = q.M21*dt;   // F2 = M21*dt*Bu
  return q;
}

// ---------------- Kernel 1: Bu = input @ Bc.T (re & im planes) ----------------
__global__ __launch_bounds__(256) void bu_gemm(const float* __restrict__ in,
                                               const float* __restrict__ B,
                                               float* __restrict__ BuRe,
                                               float* __restrict__ BuIm){
  __shared__ float4 stile[32][32];                     // 32 l-rows x 128 h
  int l0 = blockIdx.x * 32;
  const float4* gin4 = (const float4*)(in + (size_t)l0*H);
  for (int i = threadIdx.x; i < 32*32; i += 256) stile[i>>5][i&31] = gin4[i];
  __syncthreads();
  int p = threadIdx.x;
  const float4* B4 = (const float4*)(B + (size_t)p*H*2);
  float2 acc[32];
  #pragma unroll
  for (int r=0;r<32;r++) acc[r] = make_float2(0.f,0.f);
  for (int h4=0; h4<32; h4++){
    float4 b0 = B4[h4*2];
    float4 b1 = B4[h4*2+1];
    #pragma unroll
    for (int r=0;r<32;r++){
      float4 a = stile[r][h4];
      acc[r].x += a.x*b0.x + a.y*b0.z + a.z*b1.x + a.w*b1.z;
      acc[r].y += a.x*b0.y + a.y*b0.w + a.z*b1.y + a.w*b1.w;
    }
  }
  #pragma unroll
  for (int r=0;r<32;r++){
    BuRe[(size_t)(l0+r)*P + p] = acc[r].x;
    BuIm[(size_t)(l0+r)*P + p] = acc[r].y;
  }
}

// ---------------- Kernel 2: per-chunk local scan finals (zero init) ----------------
__global__ __launch_bounds__(256) void scan_finals(const float* __restrict__ BuRe,
                                                   const float* __restrict__ BuIm,
                                                   const float* __restrict__ A_diag,
                                                   const float* __restrict__ steps,
                                                   float* __restrict__ finals){
  int p = threadIdx.x;
  int c = blockIdx.x;
  int part = blockIdx.y;
  const float* Bu = part ? BuIm : BuRe;
  Params q = get_params(A_diag, steps, p);
  float x1 = 0.f, x2 = 0.f;
  const float* bp = Bu + (size_t)c*CL*P + p;
  #pragma unroll 4
  for (int i=0;i<CL;i++){
    float u = bp[(size_t)i*P];
    float n1 = q.M11*x1 + q.M12*x2 + q.s1*u;
    float n2 = q.M21*x1 + q.M22*x2 + q.s2*u;
    x1 = n1; x2 = n2;
  }
  ((float2*)finals)[(size_t)(part*NCH + c)*P + p] = make_float2(x1,x2);
}

// ---------------- Kernel 3: sequential combine over chunks -> initial carries ----------------
__global__ __launch_bounds__(512) void scan_inits(const float* __restrict__ A_diag,
                                                  const float* __restrict__ steps,
                                                  const float* __restrict__ finals,
                                                  float* __restrict__ inits){
  int tid = threadIdx.x;
  int p = tid & (P-1);
  int part = tid >> 8;
  Params q = get_params(A_diag, steps, p);
  float a=q.M11, b=q.M12, c=q.M21, d=q.M22;
  #pragma unroll
  for (int s=0;s<6;s++){            // M^64 by squaring
    float na = a*a + b*c;
    float nb = a*b + b*d;
    float nc = c*a + d*c;
    float nd = c*b + d*d;
    a=na; b=nb; c=nc; d=nd;
  }
  const float2* f2 = (const float2*)finals;
  float2* i2 = (float2*)inits;
  float x1=0.f, x2=0.f;
  #pragma unroll 8
  for (int ch=0; ch<NCH; ch++){
    size_t idx = (size_t)(part*NCH + ch)*P + p;
    i2[idx] = make_float2(x1,x2);
    float2 f = f2[idx];
    float n1 = a*x1 + b*x2 + f.x;
    float n2 = c*x1 + d*x2 + f.y;
    x1 = n1; x2 = n2;
  }
}

// ---------------- Kernel 4 (fused): scan chunk -> LDS -> ys = Re(x2 @ Cc.T) + in*D ----------
// 512 threads. Scan role: (part=tid>>8, p=tid&255). GEMM role: (grp=tid>>6, h2=tid&63),
// each thread computes h={2*h2, 2*h2+1} for 4 rows per sub-phase.
// Two 32-row sub-phases share a 64 KB LDS buffer. LDS GEMM reads are wave-uniform
// broadcasts (row & p4 uniform within a wave) -> conflict-free.
__global__ __launch_bounds__(512) void scan_out(const float* __restrict__ BuRe,
                                                const float* __restrict__ BuIm,
                                                const float* __restrict__ A_diag,
                                                const float* __restrict__ steps,
                                                const float* __restrict__ inits,
                                                const float* __restrict__ Cw,
                                                const float* __restrict__ Dv,
                                                const float* __restrict__ in,
                                                float* __restrict__ out){
  __shared__ float4 sx[2][32][64];            // [part][row][p4]  = 64 KB
  int c = blockIdx.x;
  int tid = threadIdx.x;

  // scan role
  int p = tid & (P-1);
  int part = tid >> 8;
  Params q = get_params(A_diag, steps, p);
  float2 iv = ((const float2*)inits)[(size_t)(part*NCH + c)*P + p];
  float x1 = iv.x, x2 = iv.y;
  const float* Bu = part ? BuIm : BuRe;
  const float* bp = Bu + (size_t)c*CL*P + p;

  // GEMM role
  int h2  = tid & 63;                         // h = 2*h2, 2*h2+1
  int grp = tid >> 6;                         // 8 wave-aligned row groups of 4
  const float4* C0 = (const float4*)(Cw + (size_t)(2*h2)  *P*2);
  const float4* C1 = (const float4*)(Cw + (size_t)(2*h2+1)*P*2);
  float2 dv = ((const float2*)Dv)[h2];

  for (int sub=0; sub<2; sub++){
    // ---- scan 32 rows into LDS ----
    #pragma unroll 4
    for (int i=0;i<32;i++){
      float u = bp[(size_t)(sub*32+i)*P];
      float n1 = q.M11*x1 + q.M12*x2 + q.s1*u;
      float n2 = q.M21*x1 + q.M22*x2 + q.s2*u;
      x1 = n1; x2 = n2;
      ((float*)&sx[part][i][0])[p] = x2;
    }
    __syncthreads();

    // ---- GEMM 32 rows x 128 h from LDS ----
    float acc0[4], acc1[4];
    #pragma unroll
    for (int r=0;r<4;r++){ acc0[r]=0.f; acc1[r]=0.f; }
    for (int p4=0; p4<64; p4++){
      float4 c0a = C0[p4*2], c0b = C0[p4*2+1];
      float4 c1a = C1[p4*2], c1b = C1[p4*2+1];
      #pragma unroll
      for (int r=0;r<4;r++){
        float4 xr = sx[0][grp*4+r][p4];
        float4 xi = sx[1][grp*4+r][p4];
        acc0[r] += xr.x*c0a.x - xi.x*c0a.y + xr.y*c0a.z - xi.y*c0a.w
                 + xr.z*c0b.x - xi.z*c0b.y + xr.w*c0b.z - xi.w*c0b.w;
        acc1[r] += xr.x*c1a.x - xi.x*c1a.y + xr.y*c1a.z - xi.y*c1a.w
                 + xr.z*c1b.x - xi.z*c1b.y + xr.w*c1b.z - xi.w*c1b.w;
      }
    }
    #pragma unroll
    for (int r=0;r<4;r++){
      int l = c*CL + sub*32 + grp*4 + r;
      float2 u2 = ((const float2*)(in + (size_t)l*H))[h2];
      ((float2*)(out + (size_t)l*H))[h2] =
          make_float2(acc0[r] + u2.x*dv.x, acc1[r] + u2.y*dv.y);
    }
    __syncthreads();   // protect LDS before next sub-phase overwrites it
  }
}

extern "C" void kernel_launch(void* const* d_in, const int* in_sizes, int n_in,
                              void* d_out, int out_size, void* d_ws, size_t ws_size,
                              hipStream_t stream) {
  const float* in     = (const float*)d_in[0];   // (L,H)
  const float* A_diag = (const float*)d_in[1];   // (P,)
  const float* B      = (const float*)d_in[2];   // (P,H,2)
  const float* Cw     = (const float*)d_in[3];   // (H,P,2)
  const float* Dv     = (const float*)d_in[4];   // (H,)
  const float* steps  = (const float*)d_in[5];   // (P,)
  float* out = (float*)d_out;

  float* ws = (float*)d_ws;
  float* BuRe   = ws;                                  // L*P floats (16MB)
  float* BuIm   = ws + (size_t)L*P;                    // L*P floats
  float* finals = ws + 2*(size_t)L*P;                  // 2*NCH*P*2 floats
  float* inits  = finals + (size_t)2*NCH*P*2;          // 2*NCH*P*2 floats

  bu_gemm<<<L/32, 256, 0, stream>>>(in, B, BuRe, BuIm);
  scan_finals<<<dim3(NCH,2), 256, 0, stream>>>(BuRe, BuIm, A_diag, steps, finals);
  scan_inits<<<1, 512, 0, stream>>>(A_diag, steps, finals, inits);
  scan_out<<<NCH, 512, 0, stream>>>(BuRe, BuIm, A_diag, steps, inits, Cw, Dv, in, out);
}

// Round 3
// 224.026 us; speedup vs baseline: 1.1652x; 1.1652x over previous
//
#include <hip/hip_runtime.h>
#include <math.h>

#define L 16384
#define H 128
#define P 256
#define CL 32
#define NCH (L/CL)   // 512

struct Params { float M11,M12,M21,M22,s1,s2; };

__device__ inline Params get_params(const float* A_diag, const float* steps, int p){
  float A = A_diag[p]; A = A > 0.f ? A : 0.f;          // relu
  float dt = 1.f/(1.f + expf(-steps[p]));              // sigmoid
  float schur = 1.f/(1.f + dt*dt*A);
  Params q;
  q.M11 = 1.f - dt*dt*A*schur;
  q.M12 = -dt*A*schur;
  q.M21 = dt*schur;
  q.M22 = schur;
  q.s1 = q.M11*dt;   // F1 = M11*dt*Bu
  q.s2 = q.M21*dt;   // F2 = M21*dt*Bu
  return q;
}

// ---- K1: Bu = input @ Bc.T (re & im) + fused per-chunk local scan finals ----
// block = 32 l-rows = exactly one chunk (CL=32); Bu rows live in registers, so
// the local scan is free of any extra memory pass.
__global__ __launch_bounds__(256) void bu_scan(const float* __restrict__ in,
                                               const float* __restrict__ B,
                                               const float* __restrict__ A_diag,
                                               const float* __restrict__ steps,
                                               float* __restrict__ BuRe,
                                               float* __restrict__ BuIm,
                                               float* __restrict__ finals){
  __shared__ float4 stile[32][32];                     // 32 l-rows x 128 h
  int c = blockIdx.x;                                  // chunk id
  int l0 = c * 32;
  const float4* gin4 = (const float4*)(in + (size_t)l0*H);
  for (int i = threadIdx.x; i < 32*32; i += 256) stile[i>>5][i&31] = gin4[i];
  __syncthreads();
  int p = threadIdx.x;
  const float4* B4 = (const float4*)(B + (size_t)p*H*2);
  float2 acc[32];
  #pragma unroll
  for (int r=0;r<32;r++) acc[r] = make_float2(0.f,0.f);
  for (int h4=0; h4<32; h4++){
    float4 b0 = B4[h4*2];
    float4 b1 = B4[h4*2+1];
    #pragma unroll
    for (int r=0;r<32;r++){
      float4 a = stile[r][h4];
      acc[r].x += a.x*b0.x + a.y*b0.z + a.z*b1.x + a.w*b1.z;
      acc[r].y += a.x*b0.y + a.y*b0.w + a.z*b1.y + a.w*b1.w;
    }
  }
  #pragma unroll
  for (int r=0;r<32;r++){
    BuRe[(size_t)(l0+r)*P + p] = acc[r].x;
    BuIm[(size_t)(l0+r)*P + p] = acc[r].y;
  }
  // fused local scan (zero init) over the 32 rows held in registers
  Params q = get_params(A_diag, steps, p);
  float r1=0.f,r2=0.f,i1=0.f,i2=0.f;
  #pragma unroll
  for (int r=0;r<32;r++){
    float ur = acc[r].x, ui = acc[r].y;
    float nr1 = q.M11*r1 + q.M12*r2 + q.s1*ur;
    float nr2 = q.M21*r1 + q.M22*r2 + q.s2*ur;
    r1=nr1; r2=nr2;
    float ni1 = q.M11*i1 + q.M12*i2 + q.s1*ui;
    float ni2 = q.M21*i1 + q.M22*i2 + q.s2*ui;
    i1=ni1; i2=ni2;
  }
  ((float2*)finals)[(size_t)(0*NCH + c)*P + p] = make_float2(r1,r2);
  ((float2*)finals)[(size_t)(1*NCH + c)*P + p] = make_float2(i1,i2);
}

// ---- K2: Ct[p][h]{re,im} = C[h][p]{re,im}  (256 KB, one-shot transpose) ----
__global__ __launch_bounds__(128) void ct_prep(const float* __restrict__ C,
                                               float* __restrict__ Ct){
  int p = blockIdx.x, h = threadIdx.x;
  float2 v = ((const float2*)C)[(size_t)h*P + p];
  ((float2*)Ct)[(size_t)p*H + h] = v;        // coalesced writes
}

// ---- K3: sequential combine over chunk finals -> per-chunk initial carries ----
__global__ __launch_bounds__(512) void scan_inits(const float* __restrict__ A_diag,
                                                  const float* __restrict__ steps,
                                                  const float* __restrict__ finals,
                                                  float* __restrict__ inits){
  int tid = threadIdx.x;
  int p = tid & (P-1);
  int part = tid >> 8;
  Params q = get_params(A_diag, steps, p);
  float a=q.M11, b=q.M12, c=q.M21, d=q.M22;
  #pragma unroll
  for (int s=0;s<5;s++){            // M^32 by squaring (log2(CL)=5)
    float na = a*a + b*c;
    float nb = a*b + b*d;
    float nc = c*a + d*c;
    float nd = c*b + d*d;
    a=na; b=nb; c=nc; d=nd;
  }
  const float2* f2 = (const float2*)finals;
  float2* i2 = (float2*)inits;
  float x1=0.f, x2=0.f;
  #pragma unroll 8
  for (int ch=0; ch<NCH; ch++){
    size_t idx = (size_t)(part*NCH + ch)*P + p;
    i2[idx] = make_float2(x1,x2);
    float2 f = f2[idx];
    float n1 = a*x1 + b*x2 + f.x;
    float n2 = c*x1 + d*x2 + f.y;
    x1 = n1; x2 = n2;
  }
}

// ---- K4: re-scan chunk with carry, overwrite Bu with x2 in place ----
__global__ __launch_bounds__(256) void scan_emit(float* __restrict__ BuRe,
                                                 float* __restrict__ BuIm,
                                                 const float* __restrict__ A_diag,
                                                 const float* __restrict__ steps,
                                                 const float* __restrict__ inits){
  int p = threadIdx.x;
  int c = blockIdx.x;
  int part = blockIdx.y;
  float* Bu = part ? BuIm : BuRe;
  Params q = get_params(A_diag, steps, p);
  float2 iv = ((const float2*)inits)[(size_t)(part*NCH + c)*P + p];
  float x1 = iv.x, x2 = iv.y;
  float* bp = Bu + (size_t)c*CL*P + p;
  #pragma unroll 4
  for (int i=0;i<CL;i++){
    float u = bp[(size_t)i*P];
    float n1 = q.M11*x1 + q.M12*x2 + q.s1*u;
    float n2 = q.M21*x1 + q.M22*x2 + q.s2*u;
    x1 = n1; x2 = n2;
    bp[(size_t)i*P] = x2;
  }
}

// ---- K5: ys = Re(x2 @ Cc.T) + in*D -----------------------------------------
// lanes span h (all 128 via float2 per lane): Ct row loads are fully coalesced
// (1 KB/wave), out/in accesses coalesced. x2 rows are wave-uniform -> scalar
// (s_load) path via readfirstlane'd wave id. No LDS, no strided vector access.
__global__ __launch_bounds__(256) void out_gemm(const float* __restrict__ x2re,
                                                const float* __restrict__ x2im,
                                                const float* __restrict__ Ct,
                                                const float* __restrict__ Dv,
                                                const float* __restrict__ in,
                                                float* __restrict__ out){
  int lane = threadIdx.x & 63;
  int wu = __builtin_amdgcn_readfirstlane((int)(threadIdx.x >> 6)); // wave id, uniform
  int l0 = blockIdx.x * 32 + wu * 8;           // this wave's 8 rows
  const float* xr0 = x2re + (size_t)l0 * P;    // uniform base -> scalar loads
  const float* xi0 = x2im + (size_t)l0 * P;
  const float4* Ct4 = (const float4*)Ct;       // Ct4[p*64 + lane] = h{2lane,2lane+1}

  float acc0[8], acc1[8];
  #pragma unroll
  for (int r=0;r<8;r++){ acc0[r]=0.f; acc1[r]=0.f; }

  #pragma unroll 4
  for (int p=0;p<P;p++){
    float4 cv = Ct4[(size_t)p*64 + lane];      // coalesced 1KB/wave
    #pragma unroll
    for (int r=0;r<8;r++){
      float sr = xr0[(size_t)r*P + p];         // wave-uniform -> s_load
      float si = xi0[(size_t)r*P + p];
      acc0[r] += sr*cv.x - si*cv.y;            // h = 2*lane
      acc1[r] += sr*cv.z - si*cv.w;            // h = 2*lane+1
    }
  }

  float2 dv = ((const float2*)Dv)[lane];
  #pragma unroll
  for (int r=0;r<8;r++){
    int l = l0 + r;
    float2 u2 = ((const float2*)(in + (size_t)l*H))[lane];
    ((float2*)(out + (size_t)l*H))[lane] =
        make_float2(acc0[r] + u2.x*dv.x, acc1[r] + u2.y*dv.y);
  }
}

extern "C" void kernel_launch(void* const* d_in, const int* in_sizes, int n_in,
                              void* d_out, int out_size, void* d_ws, size_t ws_size,
                              hipStream_t stream) {
  const float* in     = (const float*)d_in[0];   // (L,H)
  const float* A_diag = (const float*)d_in[1];   // (P,)
  const float* B      = (const float*)d_in[2];   // (P,H,2)
  const float* Cw     = (const float*)d_in[3];   // (H,P,2)
  const float* Dv     = (const float*)d_in[4];   // (H,)
  const float* steps  = (const float*)d_in[5];   // (P,)
  float* out = (float*)d_out;

  float* ws = (float*)d_ws;
  float* BuRe   = ws;                                  // L*P floats (16MB)
  float* BuIm   = BuRe + (size_t)L*P;                  // L*P floats (16MB)
  float* Ct     = BuIm + (size_t)L*P;                  // P*H*2 floats (256KB)
  float* finals = Ct + (size_t)P*H*2;                  // 2*NCH*P*2 floats (2MB)
  float* inits  = finals + (size_t)2*NCH*P*2;          // 2*NCH*P*2 floats (2MB)

  bu_scan<<<NCH, 256, 0, stream>>>(in, B, A_diag, steps, BuRe, BuIm, finals);
  ct_prep<<<P, 128, 0, stream>>>(Cw, Ct);
  scan_inits<<<1, 512, 0, stream>>>(A_diag, steps, finals, inits);
  scan_emit<<<dim3(NCH,2), 256, 0, stream>>>(BuRe, BuIm, A_diag, steps, inits);
  out_gemm<<<L/32, 256, 0, stream>>>(BuRe, BuIm, Ct, Dv, in, out);
}

// Round 4
// 173.515 us; speedup vs baseline: 1.5044x; 1.2911x over previous
//
#include <hip/hip_runtime.h>
#include <math.h>

#define L 16384
#define H 128
#define P 256
#define CL 32
#define NCH (L/CL)   // 512 chunks
#define GS 16        // chunks per group
#define NG (NCH/GS)  // 32 groups

struct Params { float M11,M12,M21,M22,s1,s2; };

__device__ inline Params get_params(const float* A_diag, const float* steps, int p){
  float A = A_diag[p]; A = A > 0.f ? A : 0.f;          // relu
  float dt = 1.f/(1.f + expf(-steps[p]));              // sigmoid
  float schur = 1.f/(1.f + dt*dt*A);
  Params q;
  q.M11 = 1.f - dt*dt*A*schur;
  q.M12 = -dt*A*schur;
  q.M21 = dt*schur;
  q.M22 = schur;
  q.s1 = q.M11*dt;   // F1 = M11*dt*Bu
  q.s2 = q.M21*dt;   // F2 = M21*dt*Bu
  return q;
}

// ---- K1: Bu = input @ Bc.T (re & im) + fused per-chunk local scan finals ----
__global__ __launch_bounds__(256) void bu_scan(const float* __restrict__ in,
                                               const float* __restrict__ B,
                                               const float* __restrict__ A_diag,
                                               const float* __restrict__ steps,
                                               float* __restrict__ BuRe,
                                               float* __restrict__ BuIm,
                                               float* __restrict__ finals){
  __shared__ float4 stile[32][32];                     // 32 l-rows x 128 h
  int c = blockIdx.x;                                  // chunk id
  int l0 = c * 32;
  const float4* gin4 = (const float4*)(in + (size_t)l0*H);
  for (int i = threadIdx.x; i < 32*32; i += 256) stile[i>>5][i&31] = gin4[i];
  __syncthreads();
  int p = threadIdx.x;
  const float4* B4 = (const float4*)(B + (size_t)p*H*2);
  float2 acc[32];
  #pragma unroll
  for (int r=0;r<32;r++) acc[r] = make_float2(0.f,0.f);
  for (int h4=0; h4<32; h4++){
    float4 b0 = B4[h4*2];
    float4 b1 = B4[h4*2+1];
    #pragma unroll
    for (int r=0;r<32;r++){
      float4 a = stile[r][h4];
      acc[r].x += a.x*b0.x + a.y*b0.z + a.z*b1.x + a.w*b1.z;
      acc[r].y += a.x*b0.y + a.y*b0.w + a.z*b1.y + a.w*b1.w;
    }
  }
  #pragma unroll
  for (int r=0;r<32;r++){
    BuRe[(size_t)(l0+r)*P + p] = acc[r].x;
    BuIm[(size_t)(l0+r)*P + p] = acc[r].y;
  }
  Params q = get_params(A_diag, steps, p);
  float r1=0.f,r2=0.f,i1=0.f,i2=0.f;
  #pragma unroll
  for (int r=0;r<32;r++){
    float ur = acc[r].x, ui = acc[r].y;
    float nr1 = q.M11*r1 + q.M12*r2 + q.s1*ur;
    float nr2 = q.M21*r1 + q.M22*r2 + q.s2*ur;
    r1=nr1; r2=nr2;
    float ni1 = q.M11*i1 + q.M12*i2 + q.s1*ui;
    float ni2 = q.M21*i1 + q.M22*i2 + q.s2*ui;
    i1=ni1; i2=ni2;
  }
  ((float2*)finals)[(size_t)(0*NCH + c)*P + p] = make_float2(r1,r2);
  ((float2*)finals)[(size_t)(1*NCH + c)*P + p] = make_float2(i1,i2);
}

// ---- K2: Ct[p][h]{re,im} = C[h][p]{re,im}  (256 KB, one-shot transpose) ----
__global__ __launch_bounds__(128) void ct_prep(const float* __restrict__ C,
                                               float* __restrict__ Ct){
  int p = blockIdx.x, h = threadIdx.x;
  float2 v = ((const float2*)C)[(size_t)h*P + p];
  ((float2*)Ct)[(size_t)p*H + h] = v;
}

// ---- K3a: per-group local scan of chunk finals (in place: finals -> z), group final -> gfin
// 32 blocks x 512 threads; 16 serial steps each. zf is BOTH input (f) and output (z):
// read f, then overwrite same slot with the group-local carry z (valid: same thread, same addr).
__global__ __launch_bounds__(512) void group_scan(const float* __restrict__ A_diag,
                                                  const float* __restrict__ steps,
                                                  float* zf,
                                                  float* __restrict__ gfin){
  int tid = threadIdx.x;
  int p = tid & (P-1);
  int part = tid >> 8;
  int g = blockIdx.x;
  Params q = get_params(A_diag, steps, p);
  float a=q.M11, b=q.M12, c=q.M21, d=q.M22;
  #pragma unroll
  for (int s=0;s<5;s++){            // T = M^32
    float na=a*a+b*c, nb=a*b+b*d, nc=c*a+d*c, nd=c*b+d*d;
    a=na;b=nb;c=nc;d=nd;
  }
  float2* z2 = (float2*)zf;
  float x1=0.f, x2=0.f;
  #pragma unroll
  for (int i=0;i<GS;i++){
    size_t idx = (size_t)(part*NCH + g*GS + i)*P + p;
    float2 f = z2[idx];             // read chunk final
    z2[idx] = make_float2(x1,x2);   // overwrite with group-local carry
    float n1 = a*x1 + b*x2 + f.x;
    float n2 = c*x1 + d*x2 + f.y;
    x1=n1; x2=n2;
  }
  ((float2*)gfin)[(size_t)(part*NG + g)*P + p] = make_float2(x1,x2);
}

// ---- K3b: serial combine of 32 group finals with T_G = M^512 -> group carries Yarr ----
__global__ __launch_bounds__(512) void group_combine(const float* __restrict__ A_diag,
                                                     const float* __restrict__ steps,
                                                     const float* __restrict__ gfin,
                                                     float* __restrict__ Yarr){
  int tid = threadIdx.x;
  int p = tid & (P-1);
  int part = tid >> 8;
  Params q = get_params(A_diag, steps, p);
  float a=q.M11, b=q.M12, c=q.M21, d=q.M22;
  #pragma unroll
  for (int s=0;s<9;s++){            // T_G = M^512
    float na=a*a+b*c, nb=a*b+b*d, nc=c*a+d*c, nd=c*b+d*d;
    a=na;b=nb;c=nc;d=nd;
  }
  const float2* Z2 = (const float2*)gfin;
  float2* Y2 = (float2*)Yarr;
  float x1=0.f, x2=0.f;
  #pragma unroll
  for (int g=0; g<NG; g++){
    size_t idx = (size_t)(part*NG + g)*P + p;
    Y2[idx] = make_float2(x1,x2);
    float2 z = Z2[idx];
    float n1 = a*x1 + b*x2 + z.x;
    float n2 = c*x1 + d*x2 + z.y;
    x1=n1; x2=n2;
  }
}

// ---- K4: re-scan chunk with carry (init = T^i * Y_g + z_c), overwrite Bu with x2 ----
__global__ __launch_bounds__(256) void scan_emit(float* __restrict__ BuRe,
                                                 float* __restrict__ BuIm,
                                                 const float* __restrict__ A_diag,
                                                 const float* __restrict__ steps,
                                                 const float* __restrict__ zloc,
                                                 const float* __restrict__ Yarr){
  int p = threadIdx.x;
  int c = blockIdx.x;
  int part = blockIdx.y;
  int g = c >> 4, iw = c & (GS-1);
  float* Bu = part ? BuIm : BuRe;
  Params q = get_params(A_diag, steps, p);
  // T = M^32
  float a=q.M11, b=q.M12, cc=q.M21, dd=q.M22;
  #pragma unroll
  for (int s=0;s<5;s++){
    float na=a*a+b*cc, nb=a*b+b*dd, nc=cc*a+dd*cc, nd=cc*b+dd*dd;
    a=na;b=nb;cc=nc;dd=nd;
  }
  // S = T^iw (powers of same matrix commute; iw is wave-uniform)
  float sa=1.f, sb=0.f, sc=0.f, sd=1.f;
  float wa=a, wb=b, wc=cc, wd=dd;
  #pragma unroll
  for (int bit=0; bit<4; bit++){
    if ((iw>>bit)&1){
      float na = wa*sa + wb*sc, nb = wa*sb + wb*sd;
      float nc = wc*sa + wd*sc, nd = wc*sb + wd*sd;
      sa=na; sb=nb; sc=nc; sd=nd;
    }
    float qa = wa*wa + wb*wc, qb = wa*wb + wb*wd;
    float qc = wc*wa + wd*wc, qd = wc*wb + wd*wd;
    wa=qa; wb=qb; wc=qc; wd=qd;
  }
  float2 Y = ((const float2*)Yarr)[(size_t)(part*NG + g)*P + p];
  float2 z = ((const float2*)zloc)[(size_t)(part*NCH + c)*P + p];
  float x1 = sa*Y.x + sb*Y.y + z.x;
  float x2 = sc*Y.x + sd*Y.y + z.y;

  float* bp = Bu + (size_t)c*CL*P + p;
  #pragma unroll 4
  for (int i=0;i<CL;i++){
    float u = bp[(size_t)i*P];
    float n1 = q.M11*x1 + q.M12*x2 + q.s1*u;
    float n2 = q.M21*x1 + q.M22*x2 + q.s2*u;
    x1 = n1; x2 = n2;
    bp[(size_t)i*P] = x2;
  }
}

// ---- K5: ys = Re(x2 @ Cc.T) + in*D -----------------------------------------
__global__ __launch_bounds__(256) void out_gemm(const float* __restrict__ x2re,
                                                const float* __restrict__ x2im,
                                                const float* __restrict__ Ct,
                                                const float* __restrict__ Dv,
                                                const float* __restrict__ in,
                                                float* __restrict__ out){
  int lane = threadIdx.x & 63;
  int wu = __builtin_amdgcn_readfirstlane((int)(threadIdx.x >> 6));
  int l0 = blockIdx.x * 32 + wu * 8;
  const float* xr0 = x2re + (size_t)l0 * P;    // uniform base -> scalar loads
  const float* xi0 = x2im + (size_t)l0 * P;
  const float4* Ct4 = (const float4*)Ct;

  float acc0[8], acc1[8];
  #pragma unroll
  for (int r=0;r<8;r++){ acc0[r]=0.f; acc1[r]=0.f; }

  #pragma unroll 4
  for (int p=0;p<P;p++){
    float4 cv = Ct4[(size_t)p*64 + lane];
    #pragma unroll
    for (int r=0;r<8;r++){
      float sr = xr0[(size_t)r*P + p];
      float si = xi0[(size_t)r*P + p];
      acc0[r] += sr*cv.x - si*cv.y;
      acc1[r] += sr*cv.z - si*cv.w;
    }
  }

  float2 dv = ((const float2*)Dv)[lane];
  #pragma unroll
  for (int r=0;r<8;r++){
    int l = l0 + r;
    float2 u2 = ((const float2*)(in + (size_t)l*H))[lane];
    ((float2*)(out + (size_t)l*H))[lane] =
        make_float2(acc0[r] + u2.x*dv.x, acc1[r] + u2.y*dv.y);
  }
}

extern "C" void kernel_launch(void* const* d_in, const int* in_sizes, int n_in,
                              void* d_out, int out_size, void* d_ws, size_t ws_size,
                              hipStream_t stream) {
  const float* in     = (const float*)d_in[0];   // (L,H)
  const float* A_diag = (const float*)d_in[1];   // (P,)
  const float* B      = (const float*)d_in[2];   // (P,H,2)
  const float* Cw     = (const float*)d_in[3];   // (H,P,2)
  const float* Dv     = (const float*)d_in[4];   // (H,)
  const float* steps  = (const float*)d_in[5];   // (P,)
  float* out = (float*)d_out;

  float* ws = (float*)d_ws;
  float* BuRe   = ws;                                  // L*P (16MB)
  float* BuIm   = BuRe + (size_t)L*P;                  // L*P (16MB)
  float* Ct     = BuIm + (size_t)L*P;                  // P*H*2 (256KB)
  float* finals = Ct + (size_t)P*H*2;                  // 2*NCH*P*2 (2MB) — becomes zloc in place
  float* gfin   = finals + (size_t)2*NCH*P*2;          // 2*NG*P*2 (128KB)
  float* Yarr   = gfin + (size_t)2*NG*P*2;             // 2*NG*P*2 (128KB)

  bu_scan<<<NCH, 256, 0, stream>>>(in, B, A_diag, steps, BuRe, BuIm, finals);
  ct_prep<<<P, 128, 0, stream>>>(Cw, Ct);
  group_scan<<<NG, 512, 0, stream>>>(A_diag, steps, finals, gfin);
  group_combine<<<1, 512, 0, stream>>>(A_diag, steps, gfin, Yarr);
  scan_emit<<<dim3(NCH,2), 256, 0, stream>>>(BuRe, BuIm, A_diag, steps, finals, Yarr);
  out_gemm<<<L/32, 256, 0, stream>>>(BuRe, BuIm, Ct, Dv, in, out);
}